// Round 2
// baseline (239.872 us; speedup 1.0000x reference)
//
#include <hip/hip_runtime.h>

// GlobalGatedUpdater, round 5: R4's fill-shaped streaming + graph-fastest dispatch.
//
// R4 post-mortem: contiguous per-block stores fixed the DRAM thrash (BW 2.4 ->
// ~3.6 TB/s) but the "emb re-reads are LLC-resident" assumption failed: grid
// was (chunk-fastest), so graph b+1 re-read each emb slice ~25 ms of write
// traffic later -- the 204.8 MB/iter write stream had long evicted it from L3.
// 16x12.8 MB HBM re-reads doubled traffic: 409.6 MB @ 3.6 TB/s ~= 114 us,
// a net regression vs R3's 217 MB @ 2.4 TB/s ~= 92 us.
//
// R5: grid(B, chunks) -- blockIdx.x = graph, dispatched fastest. The 16 blocks
// consuming the SAME 20 KB emb slice are adjacent in dispatch (2 per XCD):
// one HBM miss, 15 L2/L3 hits. Expected traffic: 204.8 MB write + ~13 MB read.
// Store pattern unchanged: one contiguous 20 KB stream per block.

#define DIM 64
#define SEGS (DIM / 4)          // 16 float4 per row
#define BLOCK 256
#define KF 5                    // float4 per thread
#define TILE (BLOCK * KF)       // 1280 float4 = 20 KB per block
#define NROWS (TILE / SEGS)     // 80 rows per block-tile

__global__ __launch_bounds__(BLOCK) void ggu_stream(
    const int* __restrict__ nodes,        // (B*n)
    const float4* __restrict__ feat,      // (B*n, SEGS)
    const float4* __restrict__ emb,       // (items, SEGS)
    const float* __restrict__ alpha,      // (items)
    float4* __restrict__ out,             // (B, items, SEGS)
    int items, int n)
{
    const int b = blockIdx.x;                            // graph: dispatch-fastest
    const size_t rowsF4 = (size_t)items * SEGS;          // 800000 float4 / graph
    const size_t base   = (size_t)blockIdx.y * TILE;     // float4 offset in graph
    const int row0      = (int)(base / SEGS);            // first row of this tile

    // last_j[local_row] = last j in graph b touching that row, else -1
    __shared__ int lastj[NROWS];
    for (int i = threadIdx.x; i < NROWS; i += BLOCK) lastj[i] = -1;
    __syncthreads();
    for (int j = threadIdx.x; j < n; j += BLOCK) {
        const int local = nodes[b * n + j] - row0;
        if ((unsigned)local < (unsigned)NROWS)
            atomicMax(&lastj[local], j);                 // max j == last write wins
    }
    __syncthreads();

    const float4* e = emb + base;
    float4* o = out + (size_t)b * rowsF4 + base;

    #pragma unroll
    for (int k = 0; k < KF; ++k) {
        const int off = k * BLOCK + (int)threadIdx.x;    // 0..TILE-1
        if (base + (size_t)off < rowsF4) {
            float4 v = e[off];                           // 1 HBM miss + 15 cache hits
            const int jl = lastj[off >> 4];              // one broadcast LDS read
            if (jl >= 0) {                               // rare: ~800/800000 rows
                const int row = row0 + (off >> 4);
                const float a = alpha[row];
                const float4 f = feat[(size_t)(b * n + jl) * SEGS + (off & (SEGS - 1))];
                const float om = 1.0f - a;
                v.x = om * v.x + a * f.x;
                v.y = om * v.y + a * f.y;
                v.z = om * v.z + a * f.z;
                v.w = om * v.w + a * f.w;
            }
            o[off] = v;                                  // contiguous stream store
        }
    }
}

extern "C" void kernel_launch(void* const* d_in, const int* in_sizes, int n_in,
                              void* d_out, int out_size, void* d_ws, size_t ws_size,
                              hipStream_t stream) {
    const int*   nodes = (const int*)d_in[0];
    const float* feat  = (const float*)d_in[1];
    const float* emb   = (const float*)d_in[2];
    const float* alpha = (const float*)d_in[3];

    const int items = in_sizes[3];                 // 50000 (alpha element count)
    const int B     = out_size / (items * DIM);    // 16
    const int n     = in_sizes[0] / B;             // 50

    const size_t rowsF4 = (size_t)items * SEGS;    // 800000
    const unsigned gy = (unsigned)((rowsF4 + TILE - 1) / TILE);  // 625
    dim3 grid((unsigned)B, gy);                    // graph fastest, 10000 blocks

    ggu_stream<<<grid, BLOCK, 0, stream>>>(
        nodes, (const float4*)feat, (const float4*)emb, alpha,
        (float4*)d_out, items, n);
}

// Round 3
// 220.305 us; speedup vs baseline: 1.0888x; 1.0888x over previous
//
#include <hip/hip_runtime.h>

// GlobalGatedUpdater, round 6: read emb ONCE per slice, broadcast-store B times.
//
// R5 post-mortem: graph-fastest dispatch did NOT make the 16x emb re-reads
// cache-hit (kernel ~118 us == R4). Implied BW: 410 MB / 118 us = 3.47 TB/s
// (normal mixed-stream rate) vs 1.85 TB/s if reads had hit -> the re-reads
// were HBM misses despite dispatch adjacency. Per-XCD L2s are private and the
// 205 MB/iter write-allocate stream churns the memory-side L3 faster than
// cross-XCD reuse can land. Lesson: don't bet on cache policy; remove the
// re-reads structurally.
//
// R6: one block = one contiguous 20 KB emb slice, loaded ONCE into registers
// (5 float4/thread). Outer loop over B graphs, inner loop over the slice:
// each graph gets one contiguous 20 KB burst (R4's fill-shaped store pattern,
// which measured ~3.5 TB/s mixed / 6.7 TB/s pure). Traffic = algorithmic
// floor: 12.8 MB read + 204.8 MB write. Patching via per-block LDS
// lastj[B][80] (atomicMax on global node idx == last-write-wins) + a
// touched-graph bitmask so ~99% of (block,graph) pairs are pure stores.

#define DIM 64
#define SEGS (DIM / 4)          // 16 float4 per row
#define BLOCK 256
#define KF 5                    // float4 per thread
#define TILE (BLOCK * KF)       // 1280 float4 = 20 KB per block
#define NROWS (TILE / SEGS)     // 80 rows per block-tile

template <int CB>  // CB = compile-time B (0 = runtime fallback)
__global__ __launch_bounds__(BLOCK) void ggu_bcast(
    const int* __restrict__ nodes,        // (B*n)
    const float4* __restrict__ feat,      // (B*n, SEGS)
    const float4* __restrict__ emb,       // (items, SEGS)
    const float* __restrict__ alpha,      // (items)
    float4* __restrict__ out,             // (B, items, SEGS)
    int items, int n, int Brt)
{
    const int B = (CB > 0) ? CB : Brt;
    const size_t rowsF4 = (size_t)items * SEGS;          // 800000 float4 / graph
    const size_t base   = (size_t)blockIdx.x * TILE;     // float4 offset in graph
    const int row0      = (int)(base / SEGS);
    const int tid       = threadIdx.x;

    extern __shared__ int smem[];
    int* lastj = smem;                                   // B*NROWS entries
    unsigned* tmaskp = (unsigned*)(smem + B * NROWS);    // touched-graph bitmask

    for (int t = tid; t < B * NROWS; t += BLOCK) lastj[t] = -1;
    if (tid == 0) *tmaskp = 0u;
    __syncthreads();
    const int total = B * n;                             // 800
    for (int t = tid; t < total; t += BLOCK) {
        const int local = nodes[t] - row0;
        if ((unsigned)local < (unsigned)NROWS) {
            const int b = t / n;
            atomicMax(&lastj[b * NROWS + local], t);     // t monotone in j per b
            atomicOr(tmaskp, 1u << b);
        }
    }
    __syncthreads();
    const unsigned tm = *tmaskp;                         // uniform broadcast

    // Load this block's 20 KB emb slice ONCE.
    float4 v[KF];
    const float4* e = emb + base;
    #pragma unroll
    for (int k = 0; k < KF; ++k) {
        const size_t off = (size_t)(k * BLOCK + tid);
        v[k] = (base + off < rowsF4) ? e[off] : float4{0, 0, 0, 0};
    }

    // B contiguous 20 KB bursts.
    for (int b = 0; b < B; ++b) {
        float4* ob = out + (size_t)b * rowsF4 + base;
        if (!((tm >> b) & 1u)) {
            // Common path: pure broadcast of the register slice.
            #pragma unroll
            for (int k = 0; k < KF; ++k) {
                const size_t off = (size_t)(k * BLOCK + tid);
                if (base + off < rowsF4) ob[off] = v[k];
            }
        } else {
            #pragma unroll
            for (int k = 0; k < KF; ++k) {
                const size_t off = (size_t)(k * BLOCK + tid);
                if (base + off >= rowsF4) continue;
                float4 t4 = v[k];
                const int ioff = k * BLOCK + tid;
                const int jl = lastj[b * NROWS + (ioff >> 4)];
                if (jl >= 0) {                           // rare: ~0.1% of rows
                    const int row = row0 + (ioff >> 4);
                    const float a = alpha[row];
                    const float4 f = feat[(size_t)jl * SEGS + (ioff & (SEGS - 1))];
                    const float om = 1.0f - a;
                    t4.x = om * t4.x + a * f.x;
                    t4.y = om * t4.y + a * f.y;
                    t4.z = om * t4.z + a * f.z;
                    t4.w = om * t4.w + a * f.w;
                }
                ob[off] = t4;
            }
        }
    }
}

extern "C" void kernel_launch(void* const* d_in, const int* in_sizes, int n_in,
                              void* d_out, int out_size, void* d_ws, size_t ws_size,
                              hipStream_t stream) {
    const int*   nodes = (const int*)d_in[0];
    const float* feat  = (const float*)d_in[1];
    const float* emb   = (const float*)d_in[2];
    const float* alpha = (const float*)d_in[3];

    const int items = in_sizes[3];                 // 50000
    const int B     = out_size / (items * DIM);    // 16
    const int n     = in_sizes[0] / B;             // 50

    const size_t rowsF4 = (size_t)items * SEGS;    // 800000
    const unsigned grid = (unsigned)((rowsF4 + TILE - 1) / TILE);  // 625
    const size_t lds_bytes = (size_t)(B * NROWS + 1) * sizeof(int); // ~5.1 KB

    if (B == 16) {
        ggu_bcast<16><<<grid, BLOCK, lds_bytes, stream>>>(
            nodes, (const float4*)feat, (const float4*)emb, alpha,
            (float4*)d_out, items, n, B);
    } else {
        ggu_bcast<0><<<grid, BLOCK, lds_bytes, stream>>>(
            nodes, (const float4*)feat, (const float4*)emb, alpha,
            (float4*)d_out, items, n, B);
    }
}